// Round 3
// baseline (28.723 us; speedup 1.0000x reference)
//
#include <hip/hip_runtime.h>
#include <math.h>

#define NF 64
#define NC 16
#define LEN 2048
#define BATCH 256
#define BETA 2.5f
#define KAPPA 10.0f
#define EPSN 1e-12f
#define LOG2E 1.4426950408889634f

#define SPLIT 2
#define HALF (LEN / SPLIT)          // 1024 t's per block
#define TPB 1024
#define NQ (TPB / NF)               // 16 waves (q-groups) per block
#define NS (SPLIT * NQ)             // 32 partials per (b,f)
#define CHUNK (HALF / NQ)           // 64 t's per thread
#define CHUNK_MONO (LEN / NQ)       // 128 t's per thread (fallback)

__device__ __forceinline__ float clip01(float v) { return fminf(fmaxf(v, 0.0f), 1.0f); }

__device__ __forceinline__ float fexp2(float x) {
#if __has_builtin(__builtin_amdgcn_exp2f)
    return __builtin_amdgcn_exp2f(x);
#else
    return exp2f(x);
#endif
}

// ---------------------------------------------------------------------------
// Kernel 1: blocks 0..511 fill lwT[t*NF+f] = log2(w(f,t)+eps);
//           block 512 computes the reg scalar -> out[BATCH].
// ---------------------------------------------------------------------------
__global__ __launch_bounds__(256) void lw_reg_kernel(
    const float* __restrict__ t1, const float* __restrict__ t2,
    const float* __restrict__ p1, const float* __restrict__ p2,
    const float* __restrict__ tvt, const float* __restrict__ tvl1,
    const float* __restrict__ tvl2, float* __restrict__ lwT,
    float* __restrict__ out) {
    const int bid = blockIdx.x;
    const int tid = threadIdx.x;

    if (bid == (NF * LEN) / 256) {
        // ---- reg scalar ----
        __shared__ float red[256];
        float acc = 0.0f;
        for (int i = tid; i < NC * NF; i += 256) {
            float p = clip01(p1[i]);
            acc += 0.01f * (p * (1.0f - p)) + 0.01f * (p * p);
        }
        if (tid < NC) {
            float p = clip01(p2[tid]);
            acc += 0.01f * (p * (1.0f - p)) + 0.01f * (p * p);
        }
        if (tid < NF) {
            float c = clip01(tvt[tid]);
            acc += 0.01f * (c * (1.0f - c));
        }
        if (tid < NC) {
            float c = clip01(tvl1[tid]);
            acc += 0.01f * (c * (1.0f - c));
        }
        if (tid == 0) {
            float c = clip01(tvl2[0]);
            acc += 0.01f * (c * (1.0f - c));
        }
        red[tid] = acc;
        __syncthreads();
        for (int s = 128; s > 0; s >>= 1) {
            if (tid < s) red[tid] += red[tid + s];
            __syncthreads();
        }
        if (tid == 0) out[BATCH] = red[0];
        return;
    }

    // ---- lwT fill ----
    int idx = bid * 256 + tid;          // idx = t*NF + f
    int f = idx & (NF - 1);
    int t = idx >> 6;
    float t1c = fminf(fmaxf(t1[f], 0.0f), (float)(LEN - 1));
    float t2c = fminf(fmaxf(t2[f], 0.0f), (float)(LEN - 1));
    t1c = fminf(t1c, t2c - 1.0f);
    float su = 1.0f / (1.0f + __expf(-BETA * ((float)t - t1c)));
    float sv = 1.0f / (1.0f + __expf(-BETA * (t2c - (float)t)));
    lwT[idx] = __log2f(su * sv + EPSN);
}

// ---------------------------------------------------------------------------
// Kernel 2: grid = BATCH*SPLIT blocks x 1024. Single-pass exp2 accumulation;
// each wave writes its partial float4 directly to ws (no block reduction,
// no trailing barrier).
// part layout: part[b*NS + s]*NF + f,  s = h*NQ + q.
// ---------------------------------------------------------------------------
__global__ __launch_bounds__(TPB) void main_split(
    const float* __restrict__ x, const float* __restrict__ av,
    const float* __restrict__ bv, const float* __restrict__ lwT,
    float4* __restrict__ part) {
    __shared__ float xs[HALF * 2];         // 8 KB

    const int b = blockIdx.x >> 1;
    const int h = blockIdx.x & 1;
    const int tid = threadIdx.x;
    const int f = tid & (NF - 1);
    const int q = tid >> 6;

    // stage this half of x[b]: 2048 floats, one float2 per thread
    ((float2*)xs)[tid] = ((const float2*)(x + (size_t)b * (LEN * 2) + h * (HALF * 2)))[tid];

    const float a = av[f];
    const float bb = bv[f];
    const int ch = f & 1;
    const float B2 = BETA * LOG2E;

    __syncthreads();

    const int lt0 = q * CHUNK;
    const float* lwp = lwT + (size_t)(h * HALF + lt0) * NF + f;

    float sp = 0.f, wp = 0.f, sm = 0.f, wm = 0.f;
#pragma unroll 8
    for (int k = 0; k < CHUNK; ++k) {
        float lw2 = lwp[k * NF];
        float xv = xs[2 * (lt0 + k) + ch];
        float rp = fmaf(a, xv, -bb);
        float ep = fexp2(fmaf(B2, rp, lw2));
        float em = fexp2(fmaf(-B2, rp, lw2));
        sp += ep;
        wp = fmaf(ep, rp, wp);
        sm += em;
        wm = fmaf(em, rp, wm);
    }

    const int s = h * NQ + q;
    part[((size_t)b * NS + s) * NF + f] = make_float4(sp, wp, sm, wm);
}

// ---------------------------------------------------------------------------
// Kernel 3: combine 32 partials -> r1[f]; stage2 (single pass, no max);
// stage3 (single pass, no max). grid = BATCH x 64.
// Exponent-range safety: |r1|,|r2| <= ~6 -> |K*log2e*r| <= ~87;
// log2(p+eps) in [-40, 0] -> all exp2 args within +-127. No overflow,
// no full-flush-to-zero of a dominant term.
// ---------------------------------------------------------------------------
__global__ __launch_bounds__(64) void finish_kernel(
    const float4* __restrict__ part, const float* __restrict__ p1,
    const float* __restrict__ p2, const float* __restrict__ tvt_,
    const float* __restrict__ tvl1_, const float* __restrict__ tvl2_,
    float* __restrict__ out) {
    __shared__ float r1s[NF];
    __shared__ float lp[NC][NF];
    __shared__ float r2s[NC];

    const int b = blockIdx.x;
    const int f = threadIdx.x;
    const float KL = KAPPA * LOG2E;

    float Sp = 0.f, Wp = 0.f, Sm = 0.f, Wm = 0.f;
#pragma unroll
    for (int s = 0; s < NS; ++s) {
        float4 v = part[((size_t)b * NS + s) * NF + f];
        Sp += v.x; Wp += v.y; Sm += v.z; Wm += v.w;
    }
    float tvt = clip01(tvt_[f]);
    r1s[f] = tvt * (Wp / Sp) + (1.0f - tvt) * (Wm / Sm);

#pragma unroll
    for (int c = 0; c < NC; ++c)
        lp[c][f] = __log2f(clip01(p1[c * NF + f]) + EPSN);
    __syncthreads();

    if (f < NC) {
        const int c = f;
        float so = 0.f, wo = 0.f, sa = 0.f, wa = 0.f;
#pragma unroll
        for (int ff = 0; ff < NF; ++ff) {
            float r1v = r1s[ff];
            float z = KL * r1v;
            float l = lp[c][ff];
            float eo = fexp2(z + l);
            float ea = fexp2(l - z);
            so += eo; wo = fmaf(eo, r1v, wo);
            sa += ea; wa = fmaf(ea, r1v, wa);
        }
        float tvl1 = clip01(tvl1_[c]);
        r2s[c] = tvl1 * (wo / so) + (1.0f - tvl1) * (wa / sa);
    }
    __syncthreads();

    if (f == 0) {
        float so = 0.f, wo = 0.f, sa = 0.f, wa = 0.f;
#pragma unroll
        for (int c = 0; c < NC; ++c) {
            float l = __log2f(clip01(p2[c]) + EPSN);
            float r2v = r2s[c];
            float z = KL * r2v;
            float eo = fexp2(z + l);
            float ea = fexp2(l - z);
            so += eo; wo = fmaf(eo, r2v, wo);
            sa += ea; wa = fmaf(ea, r2v, wa);
        }
        float tvl2 = clip01(tvl2_[0]);
        out[b] = tvl2 * (wo / so) + (1.0f - tvl2) * (wa / sa);
    }
}

// ---------------------------------------------------------------------------
// Fallback (mono) kernel: whole pipeline per block, no workspace needed.
// ---------------------------------------------------------------------------
__global__ __launch_bounds__(TPB) void main_mono(
    const float* __restrict__ x, const float* __restrict__ av,
    const float* __restrict__ bv,
    const float* __restrict__ t1g, const float* __restrict__ t2g,
    const float* __restrict__ p1, const float* __restrict__ p2,
    const float* __restrict__ tvt_, const float* __restrict__ tvl1_,
    const float* __restrict__ tvl2_, float* __restrict__ out) {
    __shared__ float xs[LEN * 2];
    __shared__ float4 redQ[NQ][NF];
    __shared__ float lp[NC][NF];
    __shared__ float r1s[NF];
    __shared__ float r2s[NC];

    const int b = blockIdx.x;
    const int tid = threadIdx.x;
    const int f = tid & (NF - 1);
    const int q = tid >> 6;
    const float B2 = BETA * LOG2E;
    const float KL = KAPPA * LOG2E;

    ((float4*)xs)[tid] = ((const float4*)(x + (size_t)b * (LEN * 2)))[tid];

    const float a = av[f];
    const float bb = bv[f];
    const int ch = f & 1;

    float t1c = fminf(fmaxf(t1g[f], 0.0f), (float)(LEN - 1));
    float t2c = fminf(fmaxf(t2g[f], 0.0f), (float)(LEN - 1));
    t1c = fminf(t1c, t2c - 1.0f);
    __syncthreads();

    const int t0 = q * CHUNK_MONO;
    float sp = 0.f, wp = 0.f, sm = 0.f, wm = 0.f;
#pragma unroll 8
    for (int k = 0; k < CHUNK_MONO; ++k) {
        int t = t0 + k;
        float su = 1.0f / (1.0f + __expf(-BETA * ((float)t - t1c)));
        float sv = 1.0f / (1.0f + __expf(-BETA * (t2c - (float)t)));
        float lw2 = __log2f(su * sv + EPSN);
        float xv = xs[2 * t + ch];
        float rp = fmaf(a, xv, -bb);
        float ep = fexp2(fmaf(B2, rp, lw2));
        float em = fexp2(fmaf(-B2, rp, lw2));
        sp += ep; wp = fmaf(ep, rp, wp);
        sm += em; wm = fmaf(em, rp, wm);
    }
    redQ[q][f] = make_float4(sp, wp, sm, wm);
    {
        float pv = clip01(p1[tid]);
        ((float*)lp)[tid] = __log2f(pv + EPSN);
    }
    __syncthreads();

    if (q == 0) {
        float Sp = 0.f, Wp = 0.f, Sm = 0.f, Wm = 0.f;
#pragma unroll
        for (int j = 0; j < NQ; ++j) {
            float4 v = redQ[j][f];
            Sp += v.x; Wp += v.y; Sm += v.z; Wm += v.w;
        }
        float tvt = clip01(tvt_[f]);
        r1s[f] = tvt * (Wp / Sp) + (1.0f - tvt) * (Wm / Sm);
    }
    __syncthreads();

    if (tid < NC) {
        const int c = tid;
        float so = 0.f, wo = 0.f, sa = 0.f, wa = 0.f;
#pragma unroll
        for (int ff = 0; ff < NF; ++ff) {
            float r1v = r1s[ff];
            float z = KL * r1v;
            float l = lp[c][ff];
            float eo = fexp2(z + l);
            float ea = fexp2(l - z);
            so += eo; wo = fmaf(eo, r1v, wo);
            sa += ea; wa = fmaf(ea, r1v, wa);
        }
        float tvl1 = clip01(tvl1_[c]);
        r2s[c] = tvl1 * (wo / so) + (1.0f - tvl1) * (wa / sa);
    }
    __syncthreads();

    if (tid == 0) {
        float so = 0.f, wo = 0.f, sa = 0.f, wa = 0.f;
#pragma unroll
        for (int c = 0; c < NC; ++c) {
            float l = __log2f(clip01(p2[c]) + EPSN);
            float r2v = r2s[c];
            float z = KL * r2v;
            float eo = fexp2(z + l);
            float ea = fexp2(l - z);
            so += eo; wo = fmaf(eo, r2v, wo);
            sa += ea; wa = fmaf(ea, r2v, wa);
        }
        float tvl2 = clip01(tvl2_[0]);
        out[b] = tvl2 * (wo / so) + (1.0f - tvl2) * (wa / sa);
    }
}

__global__ void reg_kernel(const float* __restrict__ p1, const float* __restrict__ p2,
                           const float* __restrict__ tvt, const float* __restrict__ tvl1,
                           const float* __restrict__ tvl2, float* __restrict__ out) {
    __shared__ float red[256];
    int tid = threadIdx.x;
    float acc = 0.0f;
    for (int i = tid; i < NC * NF; i += 256) {
        float p = clip01(p1[i]);
        acc += 0.01f * (p * (1.0f - p)) + 0.01f * (p * p);
    }
    if (tid < NC) {
        float p = clip01(p2[tid]);
        acc += 0.01f * (p * (1.0f - p)) + 0.01f * (p * p);
    }
    if (tid < NF) {
        float c = clip01(tvt[tid]);
        acc += 0.01f * (c * (1.0f - c));
    }
    if (tid < NC) {
        float c = clip01(tvl1[tid]);
        acc += 0.01f * (c * (1.0f - c));
    }
    if (tid == 0) {
        float c = clip01(tvl2[0]);
        acc += 0.01f * (c * (1.0f - c));
    }
    red[tid] = acc;
    __syncthreads();
    for (int s = 128; s > 0; s >>= 1) {
        if (tid < s) red[tid] += red[tid + s];
        __syncthreads();
    }
    if (tid == 0) out[BATCH] = red[0];
}

// ---------------------------------------------------------------------------
extern "C" void kernel_launch(void* const* d_in, const int* in_sizes, int n_in,
                              void* d_out, int out_size, void* d_ws, size_t ws_size,
                              hipStream_t stream) {
    const float* x    = (const float*)d_in[0];
    const float* t1   = (const float*)d_in[1];
    const float* t2   = (const float*)d_in[2];
    const float* a    = (const float*)d_in[3];
    const float* bv   = (const float*)d_in[4];
    const float* p1   = (const float*)d_in[5];
    const float* p2   = (const float*)d_in[6];
    const float* tvt  = (const float*)d_in[7];
    const float* tvl1 = (const float*)d_in[8];
    const float* tvl2 = (const float*)d_in[9];
    float* out = (float*)d_out;

    const size_t lw_bytes = (size_t)(NF * LEN) * sizeof(float);                   // 512 KB
    const size_t part_bytes = (size_t)BATCH * NS * NF * sizeof(float4);           // 8 MB

    if (d_ws && ws_size >= lw_bytes + part_bytes) {
        float* lwT = (float*)d_ws;
        float4* part = (float4*)((char*)d_ws + lw_bytes);
        lw_reg_kernel<<<(NF * LEN) / 256 + 1, 256, 0, stream>>>(t1, t2, p1, p2, tvt, tvl1,
                                                                tvl2, lwT, out);
        main_split<<<BATCH * SPLIT, TPB, 0, stream>>>(x, a, bv, lwT, part);
        finish_kernel<<<BATCH, 64, 0, stream>>>(part, p1, p2, tvt, tvl1, tvl2, out);
    } else {
        main_mono<<<BATCH, TPB, 0, stream>>>(x, a, bv, t1, t2, p1, p2,
                                             tvt, tvl1, tvl2, out);
        reg_kernel<<<1, 256, 0, stream>>>(p1, p2, tvt, tvl1, tvl2, out);
    }
}